// Round 16
// baseline (594.032 us; speedup 1.0000x reference)
//
#include <hip/hip_runtime.h>

#define N_NODES 50000
#define N_EDGES 800000
#define LRELU_SLOPE 0.2f
#define BN_EPS 1e-5f

typedef unsigned int u32;

__device__ __forceinline__ float lrelu(float x){ return fmaxf(x,0.f) + LRELU_SLOPE*fminf(x,0.f); }
__device__ __forceinline__ float bflo(u32 u){ return __uint_as_float(u<<16); }
__device__ __forceinline__ float bfhi(u32 u){ return __uint_as_float(u & 0xffff0000u); }
__device__ __forceinline__ u32 packbf(float a, float b){
  u32 ua = __float_as_uint(a); ua = (ua + 0x7fffu + ((ua>>16)&1u)) >> 16;
  u32 ub = __float_as_uint(b); ub = (ub + 0x7fffu + ((ub>>16)&1u)) >> 16;
  return ua | (ub<<16);
}

// ---------------- CSR build ----------------
__global__ __launch_bounds__(256) void k_hist(const int* __restrict__ eidx, const float* __restrict__ pw,
                                              int* __restrict__ cnt, float* __restrict__ deg){
  int e = blockIdx.x*256 + threadIdx.x;
  if(e < N_EDGES){
    int d = eidx[N_EDGES + e];
    atomicAdd(&cnt[d], 1);
    unsafeAtomicAdd(&deg[d], pw[e]);
  }
}

__global__ __launch_bounds__(256) void k_scan1(const int* __restrict__ cnt, int* __restrict__ rowptr,
                                               int* __restrict__ bsum){
  __shared__ int sc[256];
  int b = blockIdx.x, t = threadIdx.x;
  int i = b*256 + t;
  int v = (i < N_NODES) ? cnt[i] : 0;
  sc[t] = v;
  __syncthreads();
  for(int off=1; off<256; off<<=1){
    int x = (t>=off)? sc[t-off] : 0;
    __syncthreads();
    sc[t] += x;
    __syncthreads();
  }
  if(i < N_NODES) rowptr[i] = sc[t] - v;
  if(t == 255) bsum[b] = sc[255];
}

__global__ __launch_bounds__(256) void k_scan2(const int* __restrict__ bsum, int* __restrict__ bbase,
                                               int* __restrict__ rowptr, int* __restrict__ gstart,
                                               int* __restrict__ gend){
  __shared__ int sc[256];
  int t = threadIdx.x;
  int v = (t < 196) ? bsum[t] : 0;
  sc[t] = v;
  __syncthreads();
  for(int off=1; off<256; off<<=1){
    int x = (t>=off)? sc[t-off] : 0;
    __syncthreads();
    sc[t] += x;
    __syncthreads();
  }
  if(t < 196) bbase[t] = sc[t] - v;
  if(t == 255) rowptr[N_NODES] = sc[255];
  if(t < 64){ gstart[t] = N_NODES; gend[t] = 0; }
}

__global__ __launch_bounds__(256) void k_scan3(int* __restrict__ rowptr, const int* __restrict__ bbase){
  int b = blockIdx.x, t = threadIdx.x;
  int i = b*256 + t;
  if(i < N_NODES) rowptr[i] += bbase[b];
}

__global__ __launch_bounds__(256) void k_scatter(const int* __restrict__ eidx, const float* __restrict__ pw,
                                                 const int* __restrict__ rowptr, int* __restrict__ fill,
                                                 const float* __restrict__ deg, uint2* __restrict__ s_srcw){
  int e = blockIdx.x*256 + threadIdx.x;
  if(e < N_EDGES){
    int d = eidx[N_EDGES + e];
    int s = eidx[e];
    float ge = rsqrtf(deg[s] + 1.f) * pw[e];
    int pos = rowptr[d] + atomicAdd(&fill[d], 1);
    uint2 pr; pr.x = (u32)s; pr.y = __float_as_uint(ge);
    s_srcw[pos] = pr;
  }
}

// ---------------- GCN ----------------
__global__ __launch_bounds__(256) void k_h(const float* __restrict__ px, const float* __restrict__ gw,
                                           u32* __restrict__ hb){
  int n = blockIdx.x*256 + threadIdx.x;
  if(n >= N_NODES) return;
  float x[33];
  #pragma unroll
  for(int k=0;k<33;k++) x[k] = px[n*33+k];
  float a[33];
  for(int c=0;c<33;c++){
    float s = 0.f;
    #pragma unroll
    for(int k=0;k<33;k++) s = fmaf(x[k], gw[c*33+k], s);
    a[c] = s;
  }
  #pragma unroll
  for(int d=0;d<16;d++) hb[(size_t)n*17 + d] = packbf(a[2*d], a[2*d+1]);
  hb[(size_t)n*17 + 16] = packbf(a[32], 0.f);
}

__global__ __launch_bounds__(256) void k_gcn(const u32* __restrict__ hb, const int* __restrict__ rowptr,
                                             const uint2* __restrict__ s_srcw,
                                             const float* __restrict__ deg,
                                             const float* __restrict__ gcnb, const float* __restrict__ bnm,
                                             const float* __restrict__ bnv, const float* __restrict__ bnw,
                                             const float* __restrict__ bnb, float* __restrict__ xp1){
  int wave = threadIdx.x >> 6;
  int lane = threadIdx.x & 63;
  int n = blockIdx.x*4 + wave;
  if(n >= N_NODES) return;
  int l = lane & 15, g = lane >> 4;
  bool t0 = (l == 0);
  float dn = rsqrtf(deg[n] + 1.f);
  const u32* srow = hb + (size_t)n*17;
  u32 us  = srow[l];
  u32 ust = t0 ? srow[16] : 0u;
  float acc0, acc1, acct;
  if(g == 0){ acc0 = dn*bflo(us); acc1 = dn*bfhi(us); acct = dn*bflo(ust); }
  else      { acc0 = 0.f; acc1 = 0.f; acct = 0.f; }
  int rb = rowptr[n], re = rowptr[n+1];
  int j = rb;
  for(; j+8 <= re; j += 8){
    uint2 prA = s_srcw[j + g];
    uint2 prB = s_srcw[j + 4 + g];
    float geA = __uint_as_float(prA.y);
    float geB = __uint_as_float(prB.y);
    const u32* rA = hb + (size_t)prA.x*17;
    const u32* rB = hb + (size_t)prB.x*17;
    u32 uA  = rA[l], uB = rB[l];
    u32 utA = t0 ? rA[16] : 0u;
    u32 utB = t0 ? rB[16] : 0u;
    acc0 = fmaf(geA, bflo(uA),  fmaf(geB, bflo(uB),  acc0));
    acc1 = fmaf(geA, bfhi(uA),  fmaf(geB, bfhi(uB),  acc1));
    acct = fmaf(geA, bflo(utA), fmaf(geB, bflo(utB), acct));
  }
  if(j+4 <= re){
    uint2 pr = s_srcw[j + g];
    float ge = __uint_as_float(pr.y);
    const u32* r = hb + (size_t)pr.x*17;
    u32 u  = r[l];
    u32 ut = t0 ? r[16] : 0u;
    acc0 = fmaf(ge, bflo(u),  acc0);
    acc1 = fmaf(ge, bfhi(u),  acc1);
    acct = fmaf(ge, bflo(ut), acct);
    j += 4;
  }
  int rem = re - j;
  if(rem > 0){
    bool val = (g < rem);
    uint2 pr = s_srcw[val ? (j + g) : j];
    float ge = val ? __uint_as_float(pr.y) : 0.f;
    const u32* r = hb + (size_t)pr.x*17;
    u32 u  = r[l];
    u32 ut = t0 ? r[16] : 0u;
    acc0 = fmaf(ge, bflo(u),  acc0);
    acc1 = fmaf(ge, bfhi(u),  acc1);
    acct = fmaf(ge, bflo(ut), acct);
  }
  #pragma unroll
  for(int m=16;m<=32;m<<=1){
    acc0 += __shfl_xor(acc0, m, 64);
    acc1 += __shfl_xor(acc1, m, 64);
    acct += __shfl_xor(acct, m, 64);
  }
  if(g == 0){
    int c0 = 2*l, c1 = 2*l+1;
    float v0 = fmaxf(dn*acc0 + gcnb[c0], 0.f);
    float v1 = fmaxf(dn*acc1 + gcnb[c1], 0.f);
    float i0 = bnw[c0] / sqrtf(bnv[c0] + BN_EPS);
    float i1 = bnw[c1] / sqrtf(bnv[c1] + BN_EPS);
    float2 o;
    o.x = v0*i0 + (bnb[c0] - bnm[c0]*i0);
    o.y = v1*i1 + (bnb[c1] - bnm[c1]*i1);
    ((float2*)(xp1 + (size_t)n*36))[l] = o;
    if(t0){
      float vt = fmaxf(dn*acct + gcnb[32], 0.f);
      float it = bnw[32] / sqrtf(bnv[32] + BN_EPS);
      float2 ot; ot.x = vt*it + (bnb[32] - bnm[32]*it); ot.y = 0.f;
      ((float2*)(xp1 + (size_t)n*36))[16] = ot;
      float2 z; z.x = 0.f; z.y = 0.f;
      ((float2*)(xp1 + (size_t)n*36))[17] = z;
    }
  }
}

// ---------------- GATv2 ----------------
// Register-tiled GEMM (R15 version, proven).
__global__ __launch_bounds__(320) void k_gatlin(const float* __restrict__ xp1, const float* __restrict__ wl,
                                                const float* __restrict__ wr, u32* __restrict__ xlb,
                                                float* __restrict__ xr){
  __shared__ float sx[64*36];
  __shared__ float swle[66*33];
  __shared__ float swlo[66*33];
  __shared__ float swre[66*33];
  __shared__ float swro[66*33];
  int t = threadIdx.x;
  int n0 = blockIdx.x*64;
  int nn = N_NODES - n0; if(nn > 64) nn = 64;
  for(int i=t;i<2178;i+=320){
    int d = i/33, k = i - d*33;
    int gb = d*66 + k;
    swle[i] = wl[gb];
    swlo[i] = wl[gb+33];
    swre[i] = wr[gb];
    swro[i] = wr[gb+33];
  }
  int xcnt = nn*36;
  for(int i=t;i<xcnt;i+=320) sx[i] = xp1[(size_t)n0*36 + i];
  __syncthreads();
  if(t >= 264) return;
  int ng = t/66, p = t - ng*66;
  int nbase = ng*16;
  float al0[16], al1[16], ar0[16], ar1[16];
  #pragma unroll
  for(int i=0;i<16;i++){ al0[i]=0.f; al1[i]=0.f; ar0[i]=0.f; ar1[i]=0.f; }
  const float* wle = swle + p*33;
  const float* wlo = swlo + p*33;
  const float* wre = swre + p*33;
  const float* wro = swro + p*33;
  for(int k=0;k<33;k++){
    float w0 = wle[k], w1 = wlo[k], w2 = wre[k], w3 = wro[k];
    const float* xcol = sx + nbase*36 + k;
    #pragma unroll
    for(int i=0;i<16;i++){
      float x = xcol[i*36];
      al0[i] = fmaf(x, w0, al0[i]);
      al1[i] = fmaf(x, w1, al1[i]);
      ar0[i] = fmaf(x, w2, ar0[i]);
      ar1[i] = fmaf(x, w3, ar1[i]);
    }
  }
  int head = (p >= 33) ? 1 : 0;
  int dd = p - 33*head;
  #pragma unroll
  for(int i=0;i<16;i++){
    int n = nbase + i;
    if(n < nn){
      size_t nidx = (size_t)(n0 + n);
      xlb[nidx*68 + head*34 + dd] = packbf(al0[i], al1[i]);
      float2 v; v.x = ar0[i]; v.y = ar1[i];
      ((float2*)xr)[nidx*66 + p] = v;
    }
  }
}

// block/node (+offset for split dispatch), 2 head-waves; 8 edges in flight.
__global__ __launch_bounds__(128) void k_gat(const int* __restrict__ rowptr, const u32* __restrict__ srcx,
                                             const u32* __restrict__ xlb, const float* __restrict__ xr,
                                             const float* __restrict__ att, const float* __restrict__ gatb,
                                             float* __restrict__ xp2, int n_off){
  int n = blockIdx.x + n_off;
  int h = threadIdx.x >> 6;
  int lane = threadIdx.x & 63;
  int l = lane & 15, g = lane >> 4;
  int base = h*66, dbase = h*34;
  bool t0 = (l == 0);
  size_t nrow = (size_t)n*132;
  const float2* xr2 = (const float2*)(xr + nrow + base);
  float2 xra = xr2[2*l], xrb = xr2[2*l+1];
  float2 xrt = t0 ? xr2[32] : make_float2(0.f,0.f);
  const float2* att2 = (const float2*)(att + base);
  float2 ata = att2[2*l], atb = att2[2*l+1];
  float2 att_t = att2[32];
  const u32* srow = xlb + (size_t)n*68 + dbase;
  uint2 su = ((const uint2*)srow)[l];
  u32 ust = t0 ? srow[32] : 0u;
  float s0 = bflo(su.x), s1 = bfhi(su.x), s2 = bflo(su.y), s3 = bfhi(su.y);
  float st0 = bflo(ust), st1 = bfhi(ust);
  float p = lrelu(s0+xra.x)*ata.x + lrelu(s1+xra.y)*ata.y
          + lrelu(s2+xrb.x)*atb.x + lrelu(s3+xrb.y)*atb.y
          + lrelu(st0+xrt.x)*att_t.x + lrelu(st1+xrt.y)*att_t.y;
  #pragma unroll
  for(int m=1;m<=8;m<<=1) p += __shfl_xor(p, m, 64);
  float e_self = p;
  float a0_, a1_, a2_, a3_, at0, at1, asum;
  if(g == 0){ a0_=s0; a1_=s1; a2_=s2; a3_=s3; at0=st0; at1=st1; asum=1.f; }
  else      { a0_=0.f; a1_=0.f; a2_=0.f; a3_=0.f; at0=0.f; at1=0.f; asum=0.f; }
  int rb = rowptr[n], re = rowptr[n+1];
  int j = rb;
  for(; j+8 <= re; j += 8){
    int sA = (int)srcx[2*(j + g)];
    int sB = (int)srcx[2*(j + 4 + g)];
    const u32* rA = xlb + (size_t)sA*68 + dbase;
    const u32* rB = xlb + (size_t)sB*68 + dbase;
    uint2 uA = ((const uint2*)rA)[l];
    uint2 uB = ((const uint2*)rB)[l];
    u32 utA = t0 ? rA[32] : 0u;
    u32 utB = t0 ? rB[32] : 0u;
    float vA0=bflo(uA.x), vA1=bfhi(uA.x), vA2=bflo(uA.y), vA3=bfhi(uA.y);
    float vB0=bflo(uB.x), vB1=bfhi(uB.x), vB2=bflo(uB.y), vB3=bfhi(uB.y);
    float wA0=bflo(utA), wA1=bfhi(utA);
    float wB0=bflo(utB), wB1=bfhi(utB);
    float pA = lrelu(vA0+xra.x)*ata.x + lrelu(vA1+xra.y)*ata.y
             + lrelu(vA2+xrb.x)*atb.x + lrelu(vA3+xrb.y)*atb.y
             + lrelu(wA0+xrt.x)*att_t.x + lrelu(wA1+xrt.y)*att_t.y;
    float pB = lrelu(vB0+xra.x)*ata.x + lrelu(vB1+xra.y)*ata.y
             + lrelu(vB2+xrb.x)*atb.x + lrelu(vB3+xrb.y)*atb.y
             + lrelu(wB0+xrt.x)*att_t.x + lrelu(wB1+xrt.y)*att_t.y;
    #pragma unroll
    for(int m=1;m<=8;m<<=1){
      pA += __shfl_xor(pA, m, 64);
      pB += __shfl_xor(pB, m, 64);
    }
    float aA = __expf(pA - e_self);
    float aB = __expf(pB - e_self);
    a0_ = fmaf(aA, vA0, fmaf(aB, vB0, a0_));
    a1_ = fmaf(aA, vA1, fmaf(aB, vB1, a1_));
    a2_ = fmaf(aA, vA2, fmaf(aB, vB2, a2_));
    a3_ = fmaf(aA, vA3, fmaf(aB, vB3, a3_));
    at0 = fmaf(aA, wA0, fmaf(aB, wB0, at0));
    at1 = fmaf(aA, wA1, fmaf(aB, wB1, at1));
    asum += aA + aB;
  }
  if(j+4 <= re){
    int s = (int)srcx[2*(j + g)];
    const u32* r = xlb + (size_t)s*68 + dbase;
    uint2 uu = ((const uint2*)r)[l];
    u32 ut = t0 ? r[32] : 0u;
    float v0=bflo(uu.x), v1=bfhi(uu.x), v2=bflo(uu.y), v3=bfhi(uu.y);
    float w0=bflo(ut), w1=bfhi(ut);
    float pp = lrelu(v0+xra.x)*ata.x + lrelu(v1+xra.y)*ata.y
             + lrelu(v2+xrb.x)*atb.x + lrelu(v3+xrb.y)*atb.y
             + lrelu(w0+xrt.x)*att_t.x + lrelu(w1+xrt.y)*att_t.y;
    #pragma unroll
    for(int m=1;m<=8;m<<=1) pp += __shfl_xor(pp, m, 64);
    float a = __expf(pp - e_self);
    a0_ = fmaf(a, v0, a0_); a1_ = fmaf(a, v1, a1_);
    a2_ = fmaf(a, v2, a2_); a3_ = fmaf(a, v3, a3_);
    at0 = fmaf(a, w0, at0); at1 = fmaf(a, w1, at1);
    asum += a;
    j += 4;
  }
  int rem = re - j;
  if(rem > 0){
    bool val = (g < rem);
    int s = val ? (int)srcx[2*(j + g)] : n;
    const u32* r = xlb + (size_t)s*68 + dbase;
    uint2 uu = ((const uint2*)r)[l];
    u32 ut = t0 ? r[32] : 0u;
    float v0=bflo(uu.x), v1=bfhi(uu.x), v2=bflo(uu.y), v3=bfhi(uu.y);
    float w0=bflo(ut), w1=bfhi(ut);
    float pp = lrelu(v0+xra.x)*ata.x + lrelu(v1+xra.y)*ata.y
             + lrelu(v2+xrb.x)*atb.x + lrelu(v3+xrb.y)*atb.y
             + lrelu(w0+xrt.x)*att_t.x + lrelu(w1+xrt.y)*att_t.y;
    #pragma unroll
    for(int m=1;m<=8;m<<=1) pp += __shfl_xor(pp, m, 64);
    float a = val ? __expf(pp - e_self) : 0.f;
    a0_ = fmaf(a, v0, a0_); a1_ = fmaf(a, v1, a1_);
    a2_ = fmaf(a, v2, a2_); a3_ = fmaf(a, v3, a3_);
    at0 = fmaf(a, w0, at0); at1 = fmaf(a, w1, at1);
    asum += a;
  }
  #pragma unroll
  for(int m=16;m<=32;m<<=1){
    a0_ += __shfl_xor(a0_, m, 64);
    a1_ += __shfl_xor(a1_, m, 64);
    a2_ += __shfl_xor(a2_, m, 64);
    a3_ += __shfl_xor(a3_, m, 64);
    at0 += __shfl_xor(at0, m, 64);
    at1 += __shfl_xor(at1, m, 64);
    asum += __shfl_xor(asum, m, 64);
  }
  float inv = 1.f/asum;
  if(g == 0){
    const float2* gb2 = (const float2*)(gatb + base);
    float2 ga = gb2[2*l], gb = gb2[2*l+1];
    float2* o2 = (float2*)(xp2 + nrow + base);
    float2 oa, ob;
    oa.x = fmaxf(a0_*inv + ga.x, 0.f); oa.y = fmaxf(a1_*inv + ga.y, 0.f);
    ob.x = fmaxf(a2_*inv + gb.x, 0.f); ob.y = fmaxf(a3_*inv + gb.y, 0.f);
    o2[2*l] = oa; o2[2*l+1] = ob;
    if(t0){
      float2 gt = gb2[32];
      float2 ot;
      ot.x = fmaxf(at0*inv + gt.x, 0.f); ot.y = fmaxf(at1*inv + gt.y, 0.f);
      o2[32] = ot;
    }
  }
}

// ---------------- pooling + MLP head ----------------
__global__ __launch_bounds__(256) void k_bounds(const int* __restrict__ batch, int* __restrict__ gstart,
                                                int* __restrict__ gend){
  int n = blockIdx.x*256 + threadIdx.x;
  if(n >= N_NODES) return;
  int b = batch[n];
  if(n == 0) gstart[b] = 0;
  else {
    int p = batch[n-1];
    if(p != b){ gstart[b] = n; gend[p] = n; }
  }
  if(n == N_NODES-1) gend[b] = N_NODES;
}

__global__ __launch_bounds__(128) void k_poolp(const float* __restrict__ xp2, const int* __restrict__ gstart,
                                               const int* __restrict__ gend, float* __restrict__ pp){
  int g = blockIdx.x, seg = blockIdx.y, t = threadIdx.x;
  int s = gstart[g], e = gend[g];
  int len = e - s; if(len < 0) len = 0;
  int ns = s + (int)(((long long)len*seg)>>4);
  int ne = s + (int)(((long long)len*(seg+1))>>4);
  float a0 = 0.f, a1 = 0.f;
  for(int n=ns;n<ne;n++){
    a0 += xp2[(size_t)n*132 + t];
    if(t < 4) a1 += xp2[(size_t)n*132 + 128 + t];
  }
  float* o = pp + (size_t)(g*16 + seg)*132;
  o[t] = a0;
  if(t < 4) o[128 + t] = a1;
}

__global__ __launch_bounds__(256) void k_pfc1(const float* __restrict__ pp, const int* __restrict__ gstart,
                                              const int* __restrict__ gend, const float* __restrict__ w,
                                              const float* __restrict__ b, float* __restrict__ h1T){
  __shared__ float pooled[132];
  int g = blockIdx.x, t = threadIdx.x;
  if(t < 132){
    float s = 0.f;
    #pragma unroll
    for(int k=0;k<16;k++) s += pp[(size_t)(g*16 + k)*132 + t];
    int c = gend[g] - gstart[g]; if(c < 1) c = 1;
    pooled[t] = s/(float)c;
  }
  __syncthreads();
  #pragma unroll
  for(int r=0;r<4;r++){
    int o = r*256 + t;
    const float* wr = w + o*132;
    float acc = b[o];
    for(int k=0;k<132;k++) acc = fmaf(pooled[k], wr[k], acc);
    h1T[o*64+g] = fmaxf(acc, 0.f);
  }
}

__global__ __launch_bounds__(256) void k_fc2(const float* __restrict__ h1T, const float* __restrict__ w,
                                             const float* __restrict__ b, float* __restrict__ out){
  __shared__ float part[256];
  int o = blockIdx.x, t = threadIdx.x;
  int s = t >> 6, g = t & 63;
  const float* wr = w + o*1024 + s*256;
  const float* hp = h1T + (size_t)(s*256)*64 + g;
  float acc = 0.f;
  for(int k=0;k<256;k++) acc = fmaf(hp[k*64], wr[k], acc);
  part[t] = acc;
  __syncthreads();
  if(s == 0){
    float r = b[o] + part[g] + part[64+g] + part[128+g] + part[192+g];
    out[8192 + g*128 + o] = r;
  }
}

// ---------------- RNA branches ----------------
__global__ __launch_bounds__(256) void k_bucket(const int* __restrict__ g, int L, int V,
                                                int* __restrict__ sci, int* __restrict__ off){
  __shared__ int gl[3000];
  __shared__ int hist[65];
  __shared__ int base[66];
  int b = blockIdx.x, t = threadIdx.x;
  if(t < V) hist[t] = 0;
  for(int i=t;i<L;i+=256) gl[i] = g[b*L + i];
  __syncthreads();
  for(int i=t;i<L;i+=256) atomicAdd(&hist[gl[i]], 1);
  __syncthreads();
  if(t == 0){
    int run = 0;
    for(int v=0;v<V;v++){ base[v] = run; run += hist[v]; }
    base[V] = run;
  }
  __syncthreads();
  if(t <= V) off[b*(V+1) + t] = base[t];
  if(t < V) hist[t] = 0;
  __syncthreads();
  for(int i=t;i<L;i+=256){
    int v = gl[i];
    int p = base[v] + atomicAdd(&hist[v], 1);
    sci[b*3000 + p] = i*8;
  }
}

__global__ __launch_bounds__(256) void k_sgather(const int* __restrict__ sci, const int* __restrict__ off,
                                                 const float* __restrict__ w, int V, int wstride,
                                                 int sstride, float* __restrict__ S){
  __shared__ int loff[66];
  __shared__ int lci[3000];
  int b = blockIdx.x, q = blockIdx.y, t = threadIdx.x;
  int nsplit = gridDim.y;
  if(t <= V) loff[t] = off[b*(V+1) + t];
  __syncthreads();
  int vs = (V*q)/nsplit, ve = (V*(q+1))/nsplit;
  if(vs == ve) return;
  int p0 = loff[vs], p1 = loff[ve];
  for(int i=p0+t;i<p1;i+=256) lci[i-p0] = sci[b*3000 + i];
  __syncthreads();
  int co = t >> 3, kk = t & 7;
  const float* wrow = w + co*wstride + kk;
  float* Srow = S + (size_t)b*32*sstride + co*sstride + kk;
  for(int v=vs;v<ve;v++){
    int j = loff[v] - p0, je = loff[v+1] - p0;
    float a0=0.f,a1=0.f,a2=0.f,a3=0.f,a4=0.f,a5=0.f,a6=0.f,a7=0.f;
    for(; j+8 <= je; j += 8){
      a0 += wrow[lci[j]];
      a1 += wrow[lci[j+1]];
      a2 += wrow[lci[j+2]];
      a3 += wrow[lci[j+3]];
      a4 += wrow[lci[j+4]];
      a5 += wrow[lci[j+5]];
      a6 += wrow[lci[j+6]];
      a7 += wrow[lci[j+7]];
    }
    for(; j<je; j++) a0 += wrow[lci[j]];
    Srow[v*8] = ((a0+a1)+(a2+a3)) + ((a4+a5)+(a6+a7));
  }
}

// k_y v2: block = (b, co-group of 8); emb staged once/block, S rows staged to LDS
// (contiguous), inner loop pure LDS+FMA. Kills the 520 VMEM broadcasts/thread and
// the 73 MB of redundant emb2 loads.
__global__ __launch_bounds__(128) void k_y(const float* __restrict__ S1, const float* __restrict__ S2,
                                           const float* __restrict__ emb1, const float* __restrict__ emb2,
                                           const float* __restrict__ c1b, const float* __restrict__ c2b,
                                           float* __restrict__ ysum){
  __shared__ float em1[640];
  __shared__ float em2[8320];
  __shared__ float Sa[320];    // 8 co x 40
  __shared__ float Sb[4160];   // 8 co x 520
  int b = blockIdx.x, cg = blockIdx.y, t = threadIdx.x;
  for(int i=t;i<640;i+=128)  em1[i] = emb1[i];
  for(int i=t;i<8320;i+=128) em2[i] = emb2[i];
  for(int i=t;i<320;i+=128)  Sa[i] = S1[b*1280 + cg*320 + i];
  for(int i=t;i<4160;i+=128) Sb[i] = S2[(size_t)b*16640 + cg*4160 + i];
  __syncthreads();
  if(t >= 121) return;
  #pragma unroll
  for(int c8=0;c8<8;c8++){
    int co = cg*8 + c8;
    const float* sa = Sa + c8*40;
    float acc1 = c1b[co];
    #pragma unroll
    for(int v=0;v<5;v++)
      #pragma unroll
      for(int k=0;k<8;k++) acc1 = fmaf(sa[v*8+k], em1[v*128 + t + k], acc1);
    const float* sb = Sb + c8*520;
    float acc2 = c2b[co];
    for(int v=0;v<65;v++){
      #pragma unroll
      for(int k=0;k<8;k++) acc2 = fmaf(sb[v*8+k], em2[v*128 + t + k], acc2);
    }
    ysum[b*3872 + co*121 + t] = 0.5f*(acc1 + acc2);
  }
}

// k_fcxr v2: 2 graphs per block -> each weight read serves two b's.
__global__ __launch_bounds__(256) void k_fcxr(const float* __restrict__ ysum, const float* __restrict__ fcw,
                                              const float* __restrict__ fcb, float* __restrict__ out){
  __shared__ float part[512];
  int bp = blockIdx.x, q = blockIdx.y, t = threadIdx.x;
  int b0 = bp*2;
  int ol = t >> 3;
  int o  = q*32 + ol;
  int slice = t & 7;
  const float4* ys0 = (const float4*)(ysum + b0*3872) + slice*121;
  const float4* ys1 = (const float4*)(ysum + (b0+1)*3872) + slice*121;
  const float4* wr  = (const float4*)(fcw + (size_t)o*3872) + slice*121;
  float acc0 = 0.f, acc1 = 0.f;
  for(int k=0;k<121;k++){
    float4 w4 = wr[k];
    float4 y0 = ys0[k], y1 = ys1[k];
    acc0 += y0.x*w4.x + y0.y*w4.y + y0.z*w4.z + y0.w*w4.w;
    acc1 += y1.x*w4.x + y1.y*w4.y + y1.z*w4.z + y1.w*w4.w;
  }
  part[t] = acc0;
  part[256+t] = acc1;
  __syncthreads();
  if(slice == 0){
    float s0 = fcb[o], s1 = fcb[o];
    #pragma unroll
    for(int i=0;i<8;i++){ s0 += part[ol*8 + i]; s1 += part[256 + ol*8 + i]; }
    out[b0*128 + o] = s0;
    out[(b0+1)*128 + o] = s1;
  }
}

extern "C" void kernel_launch(void* const* d_in, const int* in_sizes, int n_in,
                              void* d_out, int out_size, void* d_ws, size_t ws_size,
                              hipStream_t stream){
  const int*   g_rna = (const int*)  d_in[0];
  const int*   l_rna = (const int*)  d_in[1];
  const float* pro_x = (const float*)d_in[2];
  const int*   eidx  = (const int*)  d_in[3];
  const float* pro_w = (const float*)d_in[4];
  const int*   batch = (const int*)  d_in[5];
  const float* emb1  = (const float*)d_in[6];
  const float* emb2  = (const float*)d_in[7];
  const float* c1w   = (const float*)d_in[8];
  const float* c1b   = (const float*)d_in[9];
  const float* c2w   = (const float*)d_in[10];
  const float* c2b   = (const float*)d_in[11];
  const float* fcxw  = (const float*)d_in[12];
  const float* fcxb  = (const float*)d_in[13];
  const float* gcnw  = (const float*)d_in[14];
  const float* gcnb  = (const float*)d_in[15];
  const float* bnm   = (const float*)d_in[16];
  const float* bnv   = (const float*)d_in[17];
  const float* bnw   = (const float*)d_in[18];
  const float* bnb   = (const float*)d_in[19];
  const float* gwl   = (const float*)d_in[20];
  const float* gwr   = (const float*)d_in[21];
  const float* gatt  = (const float*)d_in[22];
  const float* gatb  = (const float*)d_in[23];
  const float* f1w   = (const float*)d_in[24];
  const float* f1b   = (const float*)d_in[25];
  const float* f2w   = (const float*)d_in[26];
  const float* f2b_  = (const float*)d_in[27];
  float* out = (float*)d_out;

  char* ws = (char*)d_ws;
  size_t off = 0;
  auto A = [&](size_t n)->char*{ char* p = ws + off; off = (off + n + 255) & ~(size_t)255; return p; };
  int*   cnt    = (int*)  A((size_t)N_NODES*4);
  int*   fill   = (int*)  A((size_t)N_NODES*4);
  float* deg    = (float*)A((size_t)N_NODES*4);
  size_t zero_bytes = off;
  int*   rowptr = (int*)  A((size_t)(N_NODES+1)*4);
  int*   bsum   = (int*)  A(196*4);
  int*   bbase  = (int*)  A(196*4);
  uint2* s_srcw = (uint2*)A((size_t)N_EDGES*8);
  u32*   hb     = (u32*)  A((size_t)N_NODES*17*4);
  float* xp1    = (float*)A((size_t)N_NODES*36*4);
  u32*   xlb    = (u32*)  A((size_t)N_NODES*68*4);
  float* xr     = (float*)A((size_t)N_NODES*132*4);
  float* xp2    = (float*)A((size_t)N_NODES*132*4);
  int*   gstart = (int*)  A(64*4);
  int*   gend   = (int*)  A(64*4);
  float* pp     = (float*)A((size_t)64*16*132*4);
  float* h1T    = (float*)A(1024*64*4);
  float* S1     = (float*)A((size_t)64*1280*4);
  float* S2     = (float*)A((size_t)64*16640*4);
  float* ysum   = (float*)A((size_t)64*3872*4);
  int*   sci1   = (int*)  A((size_t)64*3000*4);
  int*   off1   = (int*)  A((size_t)64*8*4);
  int*   sci2   = (int*)  A((size_t)64*3000*4);
  int*   off2   = (int*)  A((size_t)64*66*4);
  (void)ws_size; (void)in_sizes; (void)n_in; (void)out_size;

  hipMemsetAsync(ws, 0, zero_bytes, stream);

  // protein GNN pipeline
  k_hist   <<<3125, 256, 0, stream>>>(eidx, pro_w, cnt, deg);
  k_scan1  <<<196, 256, 0, stream>>>(cnt, rowptr, bsum);
  k_scan2  <<<1, 256, 0, stream>>>(bsum, bbase, rowptr, gstart, gend);
  k_scan3  <<<196, 256, 0, stream>>>(rowptr, bbase);
  k_scatter<<<3125, 256, 0, stream>>>(eidx, pro_w, rowptr, fill, deg, s_srcw);
  k_h      <<<196, 256, 0, stream>>>(pro_x, gcnw, hb);
  k_gcn    <<<12500, 256, 0, stream>>>(hb, rowptr, s_srcw, deg, gcnb, bnm, bnv, bnw, bnb, xp1);
  k_gatlin <<<782, 320, 0, stream>>>(xp1, gwl, gwr, xlb, xr);
  k_gat    <<<25000, 128, 0, stream>>>(rowptr, (const u32*)s_srcw, xlb, xr, gatt, gatb, xp2, 0);
  k_gat    <<<25000, 128, 0, stream>>>(rowptr, (const u32*)s_srcw, xlb, xr, gatt, gatb, xp2, 25000);
  k_bounds <<<196, 256, 0, stream>>>(batch, gstart, gend);
  k_poolp  <<<dim3(64,16), 128, 0, stream>>>(xp2, gstart, gend, pp);
  k_pfc1   <<<64, 256, 0, stream>>>(pp, gstart, gend, f1w, f1b, h1T);
  k_fc2    <<<128, 256, 0, stream>>>(h1T, f2w, f2b_, out);

  // RNA branches
  k_bucket <<<64, 256, 0, stream>>>(g_rna, 3000, 5, sci1, off1);
  k_bucket <<<64, 256, 0, stream>>>(l_rna, 2998, 65, sci2, off2);
  k_sgather<<<dim3(64,5), 256, 0, stream>>>(sci1, off1, c1w, 5, 24000, 40, S1);
  k_sgather<<<dim3(64,32), 256, 0, stream>>>(sci2, off2, c2w, 65, 23984, 520, S2);
  k_y      <<<dim3(64,4), 128, 0, stream>>>(S1, S2, emb1, emb2, c1b, c2b, ysum);
  k_fcxr   <<<dim3(32,4), 256, 0, stream>>>(ysum, fcxw, fcxb, out);
}

// Round 17
// 566.118 us; speedup vs baseline: 1.0493x; 1.0493x over previous
//
#include <hip/hip_runtime.h>

#define N_NODES 50000
#define N_EDGES 800000
#define LRELU_SLOPE 0.2f
#define BN_EPS 1e-5f

typedef unsigned int u32;
typedef unsigned long long u64;

__device__ __forceinline__ float lrelu(float x){ return fmaxf(x,0.f) + LRELU_SLOPE*fminf(x,0.f); }
__device__ __forceinline__ float bflo(u32 u){ return __uint_as_float(u<<16); }
__device__ __forceinline__ float bfhi(u32 u){ return __uint_as_float(u & 0xffff0000u); }
__device__ __forceinline__ u32 packbf(float a, float b){
  u32 ua = __float_as_uint(a); ua = (ua + 0x7fffu + ((ua>>16)&1u)) >> 16;
  u32 ub = __float_as_uint(b); ub = (ub + 0x7fffu + ((ub>>16)&1u)) >> 16;
  return ua | (ub<<16);
}
// packed (cnt<<40 | deg in 2^-26 fixed point)
__device__ __forceinline__ float degof(u64 p){
  return (float)(p & 0xFFFFFFFFFFull) * (1.0f/67108864.0f);
}

// ---------------- CSR build ----------------
// pk zeroed by hipMemsetAsync. One 64-bit atomic per edge (was two 32-bit:
// memory-side atomics are op-bound -> halves k_hist cost).
__global__ __launch_bounds__(256) void k_hist(const int* __restrict__ eidx, const float* __restrict__ pw,
                                              u64* __restrict__ pk){
  int e = blockIdx.x*256 + threadIdx.x;
  if(e < N_EDGES){
    int d = eidx[N_EDGES + e];
    u64 q = (u64)(pw[e] * 67108864.f);
    atomicAdd(&pk[d], (1ull<<40) | q);
  }
}

__global__ __launch_bounds__(256) void k_scan1(const u64* __restrict__ pk, int* __restrict__ rowptr,
                                               int* __restrict__ bsum){
  __shared__ int sc[256];
  int b = blockIdx.x, t = threadIdx.x;
  int i = b*256 + t;
  int v = (i < N_NODES) ? (int)(pk[i] >> 40) : 0;
  sc[t] = v;
  __syncthreads();
  for(int off=1; off<256; off<<=1){
    int x = (t>=off)? sc[t-off] : 0;
    __syncthreads();
    sc[t] += x;
    __syncthreads();
  }
  if(i < N_NODES) rowptr[i] = sc[t] - v;
  if(t == 255) bsum[b] = sc[255];
}

__global__ __launch_bounds__(256) void k_scan2(const int* __restrict__ bsum, int* __restrict__ bbase,
                                               int* __restrict__ rowptr, int* __restrict__ gstart,
                                               int* __restrict__ gend){
  __shared__ int sc[256];
  int t = threadIdx.x;
  int v = (t < 196) ? bsum[t] : 0;
  sc[t] = v;
  __syncthreads();
  for(int off=1; off<256; off<<=1){
    int x = (t>=off)? sc[t-off] : 0;
    __syncthreads();
    sc[t] += x;
    __syncthreads();
  }
  if(t < 196) bbase[t] = sc[t] - v;
  if(t == 255) rowptr[N_NODES] = sc[255];
  if(t < 64){ gstart[t] = N_NODES; gend[t] = 0; }
}

__global__ __launch_bounds__(256) void k_scan3(int* __restrict__ rowptr, const int* __restrict__ bbase){
  int b = blockIdx.x, t = threadIdx.x;
  int i = b*256 + t;
  if(i < N_NODES) rowptr[i] += bbase[b];
}

__global__ __launch_bounds__(256) void k_scatter(const int* __restrict__ eidx, const float* __restrict__ pw,
                                                 const int* __restrict__ rowptr, int* __restrict__ fill,
                                                 const u64* __restrict__ pk, uint2* __restrict__ s_srcw){
  int e = blockIdx.x*256 + threadIdx.x;
  if(e < N_EDGES){
    int d = eidx[N_EDGES + e];
    int s = eidx[e];
    float ge = rsqrtf(degof(pk[s]) + 1.f) * pw[e];
    int pos = rowptr[d] + atomicAdd(&fill[d], 1);
    uint2 pr; pr.x = (u32)s; pr.y = __float_as_uint(ge);
    s_srcw[pos] = pr;
  }
}

// ---------------- GCN ----------------
__global__ __launch_bounds__(256) void k_h(const float* __restrict__ px, const float* __restrict__ gw,
                                           u32* __restrict__ hb){
  int n = blockIdx.x*256 + threadIdx.x;
  if(n >= N_NODES) return;
  float x[33];
  #pragma unroll
  for(int k=0;k<33;k++) x[k] = px[n*33+k];
  float a[33];
  for(int c=0;c<33;c++){
    float s = 0.f;
    #pragma unroll
    for(int k=0;k<33;k++) s = fmaf(x[k], gw[c*33+k], s);
    a[c] = s;
  }
  #pragma unroll
  for(int d=0;d<16;d++) hb[(size_t)n*17 + d] = packbf(a[2*d], a[2*d+1]);
  hb[(size_t)n*17 + 16] = packbf(a[32], 0.f);
}

__global__ __launch_bounds__(256) void k_gcn(const u32* __restrict__ hb, const int* __restrict__ rowptr,
                                             const uint2* __restrict__ s_srcw,
                                             const u64* __restrict__ pk,
                                             const float* __restrict__ gcnb, const float* __restrict__ bnm,
                                             const float* __restrict__ bnv, const float* __restrict__ bnw,
                                             const float* __restrict__ bnb, float* __restrict__ xp1){
  int wave = threadIdx.x >> 6;
  int lane = threadIdx.x & 63;
  int n = blockIdx.x*4 + wave;
  if(n >= N_NODES) return;
  int l = lane & 15, g = lane >> 4;
  bool t0 = (l == 0);
  float dn = rsqrtf(degof(pk[n]) + 1.f);
  const u32* srow = hb + (size_t)n*17;
  u32 us  = srow[l];
  u32 ust = t0 ? srow[16] : 0u;
  float acc0, acc1, acct;
  if(g == 0){ acc0 = dn*bflo(us); acc1 = dn*bfhi(us); acct = dn*bflo(ust); }
  else      { acc0 = 0.f; acc1 = 0.f; acct = 0.f; }
  int rb = rowptr[n], re = rowptr[n+1];
  int j = rb;
  for(; j+8 <= re; j += 8){
    uint2 prA = s_srcw[j + g];
    uint2 prB = s_srcw[j + 4 + g];
    float geA = __uint_as_float(prA.y);
    float geB = __uint_as_float(prB.y);
    const u32* rA = hb + (size_t)prA.x*17;
    const u32* rB = hb + (size_t)prB.x*17;
    u32 uA  = rA[l], uB = rB[l];
    u32 utA = t0 ? rA[16] : 0u;
    u32 utB = t0 ? rB[16] : 0u;
    acc0 = fmaf(geA, bflo(uA),  fmaf(geB, bflo(uB),  acc0));
    acc1 = fmaf(geA, bfhi(uA),  fmaf(geB, bfhi(uB),  acc1));
    acct = fmaf(geA, bflo(utA), fmaf(geB, bflo(utB), acct));
  }
  if(j+4 <= re){
    uint2 pr = s_srcw[j + g];
    float ge = __uint_as_float(pr.y);
    const u32* r = hb + (size_t)pr.x*17;
    u32 u  = r[l];
    u32 ut = t0 ? r[16] : 0u;
    acc0 = fmaf(ge, bflo(u),  acc0);
    acc1 = fmaf(ge, bfhi(u),  acc1);
    acct = fmaf(ge, bflo(ut), acct);
    j += 4;
  }
  int rem = re - j;
  if(rem > 0){
    bool val = (g < rem);
    uint2 pr = s_srcw[val ? (j + g) : j];
    float ge = val ? __uint_as_float(pr.y) : 0.f;
    const u32* r = hb + (size_t)pr.x*17;
    u32 u  = r[l];
    u32 ut = t0 ? r[16] : 0u;
    acc0 = fmaf(ge, bflo(u),  acc0);
    acc1 = fmaf(ge, bfhi(u),  acc1);
    acct = fmaf(ge, bflo(ut), acct);
  }
  #pragma unroll
  for(int m=16;m<=32;m<<=1){
    acc0 += __shfl_xor(acc0, m, 64);
    acc1 += __shfl_xor(acc1, m, 64);
    acct += __shfl_xor(acct, m, 64);
  }
  if(g == 0){
    int c0 = 2*l, c1 = 2*l+1;
    float v0 = fmaxf(dn*acc0 + gcnb[c0], 0.f);
    float v1 = fmaxf(dn*acc1 + gcnb[c1], 0.f);
    float i0 = bnw[c0] / sqrtf(bnv[c0] + BN_EPS);
    float i1 = bnw[c1] / sqrtf(bnv[c1] + BN_EPS);
    float2 o;
    o.x = v0*i0 + (bnb[c0] - bnm[c0]*i0);
    o.y = v1*i1 + (bnb[c1] - bnm[c1]*i1);
    ((float2*)(xp1 + (size_t)n*36))[l] = o;
    if(t0){
      float vt = fmaxf(dn*acct + gcnb[32], 0.f);
      float it = bnw[32] / sqrtf(bnv[32] + BN_EPS);
      float2 ot; ot.x = vt*it + (bnb[32] - bnm[32]*it); ot.y = 0.f;
      ((float2*)(xp1 + (size_t)n*36))[16] = ot;
      float2 z; z.x = 0.f; z.y = 0.f;
      ((float2*)(xp1 + (size_t)n*36))[17] = z;
    }
  }
}

// ---------------- GATv2 ----------------
__global__ __launch_bounds__(320) void k_gatlin(const float* __restrict__ xp1, const float* __restrict__ wl,
                                                const float* __restrict__ wr, u32* __restrict__ xlb,
                                                float* __restrict__ xr){
  __shared__ float sx[64*36];
  __shared__ float swle[66*33];
  __shared__ float swlo[66*33];
  __shared__ float swre[66*33];
  __shared__ float swro[66*33];
  int t = threadIdx.x;
  int n0 = blockIdx.x*64;
  int nn = N_NODES - n0; if(nn > 64) nn = 64;
  for(int i=t;i<2178;i+=320){
    int d = i/33, k = i - d*33;
    int gb = d*66 + k;
    swle[i] = wl[gb];
    swlo[i] = wl[gb+33];
    swre[i] = wr[gb];
    swro[i] = wr[gb+33];
  }
  int xcnt = nn*36;
  for(int i=t;i<xcnt;i+=320) sx[i] = xp1[(size_t)n0*36 + i];
  __syncthreads();
  if(t >= 264) return;
  int ng = t/66, p = t - ng*66;
  int nbase = ng*16;
  float al0[16], al1[16], ar0[16], ar1[16];
  #pragma unroll
  for(int i=0;i<16;i++){ al0[i]=0.f; al1[i]=0.f; ar0[i]=0.f; ar1[i]=0.f; }
  const float* wle = swle + p*33;
  const float* wlo = swlo + p*33;
  const float* wre = swre + p*33;
  const float* wro = swro + p*33;
  for(int k=0;k<33;k++){
    float w0 = wle[k], w1 = wlo[k], w2 = wre[k], w3 = wro[k];
    const float* xcol = sx + nbase*36 + k;
    #pragma unroll
    for(int i=0;i<16;i++){
      float x = xcol[i*36];
      al0[i] = fmaf(x, w0, al0[i]);
      al1[i] = fmaf(x, w1, al1[i]);
      ar0[i] = fmaf(x, w2, ar0[i]);
      ar1[i] = fmaf(x, w3, ar1[i]);
    }
  }
  int head = (p >= 33) ? 1 : 0;
  int dd = p - 33*head;
  #pragma unroll
  for(int i=0;i<16;i++){
    int n = nbase + i;
    if(n < nn){
      size_t nidx = (size_t)(n0 + n);
      xlb[nidx*68 + head*34 + dd] = packbf(al0[i], al1[i]);
      float2 v; v.x = ar0[i]; v.y = ar1[i];
      ((float2*)xr)[nidx*66 + p] = v;
    }
  }
}

// block/node, 2 head-waves; wave = 4 x 16-lane groups; 8 edges in flight.
__global__ __launch_bounds__(128) void k_gat(const int* __restrict__ rowptr, const u32* __restrict__ srcx,
                                             const u32* __restrict__ xlb, const float* __restrict__ xr,
                                             const float* __restrict__ att, const float* __restrict__ gatb,
                                             float* __restrict__ xp2){
  int n = blockIdx.x;
  int h = threadIdx.x >> 6;
  int lane = threadIdx.x & 63;
  int l = lane & 15, g = lane >> 4;
  int base = h*66, dbase = h*34;
  bool t0 = (l == 0);
  size_t nrow = (size_t)n*132;
  const float2* xr2 = (const float2*)(xr + nrow + base);
  float2 xra = xr2[2*l], xrb = xr2[2*l+1];
  float2 xrt = t0 ? xr2[32] : make_float2(0.f,0.f);
  const float2* att2 = (const float2*)(att + base);
  float2 ata = att2[2*l], atb = att2[2*l+1];
  float2 att_t = att2[32];
  const u32* srow = xlb + (size_t)n*68 + dbase;
  uint2 su = ((const uint2*)srow)[l];
  u32 ust = t0 ? srow[32] : 0u;
  float s0 = bflo(su.x), s1 = bfhi(su.x), s2 = bflo(su.y), s3 = bfhi(su.y);
  float st0 = bflo(ust), st1 = bfhi(ust);
  float p = lrelu(s0+xra.x)*ata.x + lrelu(s1+xra.y)*ata.y
          + lrelu(s2+xrb.x)*atb.x + lrelu(s3+xrb.y)*atb.y
          + lrelu(st0+xrt.x)*att_t.x + lrelu(st1+xrt.y)*att_t.y;
  #pragma unroll
  for(int m=1;m<=8;m<<=1) p += __shfl_xor(p, m, 64);
  float e_self = p;
  float a0_, a1_, a2_, a3_, at0, at1, asum;
  if(g == 0){ a0_=s0; a1_=s1; a2_=s2; a3_=s3; at0=st0; at1=st1; asum=1.f; }
  else      { a0_=0.f; a1_=0.f; a2_=0.f; a3_=0.f; at0=0.f; at1=0.f; asum=0.f; }
  int rb = rowptr[n], re = rowptr[n+1];
  int j = rb;
  for(; j+8 <= re; j += 8){
    int sA = (int)srcx[2*(j + g)];
    int sB = (int)srcx[2*(j + 4 + g)];
    const u32* rA = xlb + (size_t)sA*68 + dbase;
    const u32* rB = xlb + (size_t)sB*68 + dbase;
    uint2 uA = ((const uint2*)rA)[l];
    uint2 uB = ((const uint2*)rB)[l];
    u32 utA = t0 ? rA[32] : 0u;
    u32 utB = t0 ? rB[32] : 0u;
    float vA0=bflo(uA.x), vA1=bfhi(uA.x), vA2=bflo(uA.y), vA3=bfhi(uA.y);
    float vB0=bflo(uB.x), vB1=bfhi(uB.x), vB2=bflo(uB.y), vB3=bfhi(uB.y);
    float wA0=bflo(utA), wA1=bfhi(utA);
    float wB0=bflo(utB), wB1=bfhi(utB);
    float pA = lrelu(vA0+xra.x)*ata.x + lrelu(vA1+xra.y)*ata.y
             + lrelu(vA2+xrb.x)*atb.x + lrelu(vA3+xrb.y)*atb.y
             + lrelu(wA0+xrt.x)*att_t.x + lrelu(wA1+xrt.y)*att_t.y;
    float pB = lrelu(vB0+xra.x)*ata.x + lrelu(vB1+xra.y)*ata.y
             + lrelu(vB2+xrb.x)*atb.x + lrelu(vB3+xrb.y)*atb.y
             + lrelu(wB0+xrt.x)*att_t.x + lrelu(wB1+xrt.y)*att_t.y;
    #pragma unroll
    for(int m=1;m<=8;m<<=1){
      pA += __shfl_xor(pA, m, 64);
      pB += __shfl_xor(pB, m, 64);
    }
    float aA = __expf(pA - e_self);
    float aB = __expf(pB - e_self);
    a0_ = fmaf(aA, vA0, fmaf(aB, vB0, a0_));
    a1_ = fmaf(aA, vA1, fmaf(aB, vB1, a1_));
    a2_ = fmaf(aA, vA2, fmaf(aB, vB2, a2_));
    a3_ = fmaf(aA, vA3, fmaf(aB, vB3, a3_));
    at0 = fmaf(aA, wA0, fmaf(aB, wB0, at0));
    at1 = fmaf(aA, wA1, fmaf(aB, wB1, at1));
    asum += aA + aB;
  }
  if(j+4 <= re){
    int s = (int)srcx[2*(j + g)];
    const u32* r = xlb + (size_t)s*68 + dbase;
    uint2 uu = ((const uint2*)r)[l];
    u32 ut = t0 ? r[32] : 0u;
    float v0=bflo(uu.x), v1=bfhi(uu.x), v2=bflo(uu.y), v3=bfhi(uu.y);
    float w0=bflo(ut), w1=bfhi(ut);
    float pp = lrelu(v0+xra.x)*ata.x + lrelu(v1+xra.y)*ata.y
             + lrelu(v2+xrb.x)*atb.x + lrelu(v3+xrb.y)*atb.y
             + lrelu(w0+xrt.x)*att_t.x + lrelu(w1+xrt.y)*att_t.y;
    #pragma unroll
    for(int m=1;m<=8;m<<=1) pp += __shfl_xor(pp, m, 64);
    float a = __expf(pp - e_self);
    a0_ = fmaf(a, v0, a0_); a1_ = fmaf(a, v1, a1_);
    a2_ = fmaf(a, v2, a2_); a3_ = fmaf(a, v3, a3_);
    at0 = fmaf(a, w0, at0); at1 = fmaf(a, w1, at1);
    asum += a;
    j += 4;
  }
  int rem = re - j;
  if(rem > 0){
    bool val = (g < rem);
    int s = val ? (int)srcx[2*(j + g)] : n;
    const u32* r = xlb + (size_t)s*68 + dbase;
    uint2 uu = ((const uint2*)r)[l];
    u32 ut = t0 ? r[32] : 0u;
    float v0=bflo(uu.x), v1=bfhi(uu.x), v2=bflo(uu.y), v3=bfhi(uu.y);
    float w0=bflo(ut), w1=bfhi(ut);
    float pp = lrelu(v0+xra.x)*ata.x + lrelu(v1+xra.y)*ata.y
             + lrelu(v2+xrb.x)*atb.x + lrelu(v3+xrb.y)*atb.y
             + lrelu(w0+xrt.x)*att_t.x + lrelu(w1+xrt.y)*att_t.y;
    #pragma unroll
    for(int m=1;m<=8;m<<=1) pp += __shfl_xor(pp, m, 64);
    float a = val ? __expf(pp - e_self) : 0.f;
    a0_ = fmaf(a, v0, a0_); a1_ = fmaf(a, v1, a1_);
    a2_ = fmaf(a, v2, a2_); a3_ = fmaf(a, v3, a3_);
    at0 = fmaf(a, w0, at0); at1 = fmaf(a, w1, at1);
    asum += a;
  }
  #pragma unroll
  for(int m=16;m<=32;m<<=1){
    a0_ += __shfl_xor(a0_, m, 64);
    a1_ += __shfl_xor(a1_, m, 64);
    a2_ += __shfl_xor(a2_, m, 64);
    a3_ += __shfl_xor(a3_, m, 64);
    at0 += __shfl_xor(at0, m, 64);
    at1 += __shfl_xor(at1, m, 64);
    asum += __shfl_xor(asum, m, 64);
  }
  float inv = 1.f/asum;
  if(g == 0){
    const float2* gb2 = (const float2*)(gatb + base);
    float2 ga = gb2[2*l], gb = gb2[2*l+1];
    float2* o2 = (float2*)(xp2 + nrow + base);
    float2 oa, ob;
    oa.x = fmaxf(a0_*inv + ga.x, 0.f); oa.y = fmaxf(a1_*inv + ga.y, 0.f);
    ob.x = fmaxf(a2_*inv + gb.x, 0.f); ob.y = fmaxf(a3_*inv + gb.y, 0.f);
    o2[2*l] = oa; o2[2*l+1] = ob;
    if(t0){
      float2 gt = gb2[32];
      float2 ot;
      ot.x = fmaxf(at0*inv + gt.x, 0.f); ot.y = fmaxf(at1*inv + gt.y, 0.f);
      o2[32] = ot;
    }
  }
}

// ---------------- pooling + MLP head ----------------
__global__ __launch_bounds__(256) void k_bounds(const int* __restrict__ batch, int* __restrict__ gstart,
                                                int* __restrict__ gend){
  int n = blockIdx.x*256 + threadIdx.x;
  if(n >= N_NODES) return;
  int b = batch[n];
  if(n == 0) gstart[b] = 0;
  else {
    int p = batch[n-1];
    if(p != b){ gstart[b] = n; gend[p] = n; }
  }
  if(n == N_NODES-1) gend[b] = N_NODES;
}

__global__ __launch_bounds__(128) void k_poolp(const float* __restrict__ xp2, const int* __restrict__ gstart,
                                               const int* __restrict__ gend, float* __restrict__ pp){
  int g = blockIdx.x, seg = blockIdx.y, t = threadIdx.x;
  int s = gstart[g], e = gend[g];
  int len = e - s; if(len < 0) len = 0;
  int ns = s + (int)(((long long)len*seg)>>4);
  int ne = s + (int)(((long long)len*(seg+1))>>4);
  float a0 = 0.f, a1 = 0.f;
  for(int n=ns;n<ne;n++){
    a0 += xp2[(size_t)n*132 + t];
    if(t < 4) a1 += xp2[(size_t)n*132 + 128 + t];
  }
  float* o = pp + (size_t)(g*16 + seg)*132;
  o[t] = a0;
  if(t < 4) o[128 + t] = a1;
}

__global__ __launch_bounds__(256) void k_pfc1(const float* __restrict__ pp, const int* __restrict__ gstart,
                                              const int* __restrict__ gend, const float* __restrict__ w,
                                              const float* __restrict__ b, float* __restrict__ h1T){
  __shared__ float pooled[132];
  int g = blockIdx.x, t = threadIdx.x;
  if(t < 132){
    float s = 0.f;
    #pragma unroll
    for(int k=0;k<16;k++) s += pp[(size_t)(g*16 + k)*132 + t];
    int c = gend[g] - gstart[g]; if(c < 1) c = 1;
    pooled[t] = s/(float)c;
  }
  __syncthreads();
  #pragma unroll
  for(int r=0;r<4;r++){
    int o = r*256 + t;
    const float* wr = w + o*132;
    float acc = b[o];
    for(int k=0;k<132;k++) acc = fmaf(pooled[k], wr[k], acc);
    h1T[o*64+g] = fmaxf(acc, 0.f);
  }
}

__global__ __launch_bounds__(256) void k_fc2(const float* __restrict__ h1T, const float* __restrict__ w,
                                             const float* __restrict__ b, float* __restrict__ out){
  __shared__ float part[256];
  int o = blockIdx.x, t = threadIdx.x;
  int s = t >> 6, g = t & 63;
  const float* wr = w + o*1024 + s*256;
  const float* hp = h1T + (size_t)(s*256)*64 + g;
  float acc = 0.f;
  for(int k=0;k<256;k++) acc = fmaf(hp[k*64], wr[k], acc);
  part[t] = acc;
  __syncthreads();
  if(s == 0){
    float r = b[o] + part[g] + part[64+g] + part[128+g] + part[192+g];
    out[8192 + g*128 + o] = r;
  }
}

// ---------------- RNA branches ----------------
__global__ __launch_bounds__(256) void k_bucket(const int* __restrict__ g, int L, int V,
                                                int* __restrict__ sci, int* __restrict__ off){
  __shared__ int gl[3000];
  __shared__ int hist[65];
  __shared__ int base[66];
  int b = blockIdx.x, t = threadIdx.x;
  if(t < V) hist[t] = 0;
  for(int i=t;i<L;i+=256) gl[i] = g[b*L + i];
  __syncthreads();
  for(int i=t;i<L;i+=256) atomicAdd(&hist[gl[i]], 1);
  __syncthreads();
  if(t == 0){
    int run = 0;
    for(int v=0;v<V;v++){ base[v] = run; run += hist[v]; }
    base[V] = run;
  }
  __syncthreads();
  if(t <= V) off[b*(V+1) + t] = base[t];
  if(t < V) hist[t] = 0;
  __syncthreads();
  for(int i=t;i<L;i+=256){
    int v = gl[i];
    int p = base[v] + atomicAdd(&hist[v], 1);
    sci[b*3000 + p] = i*8;
  }
}

__global__ __launch_bounds__(256) void k_sgather(const int* __restrict__ sci, const int* __restrict__ off,
                                                 const float* __restrict__ w, int V, int wstride,
                                                 int sstride, float* __restrict__ S){
  __shared__ int loff[66];
  __shared__ int lci[3000];
  int b = blockIdx.x, q = blockIdx.y, t = threadIdx.x;
  int nsplit = gridDim.y;
  if(t <= V) loff[t] = off[b*(V+1) + t];
  __syncthreads();
  int vs = (V*q)/nsplit, ve = (V*(q+1))/nsplit;
  if(vs == ve) return;
  int p0 = loff[vs], p1 = loff[ve];
  for(int i=p0+t;i<p1;i+=256) lci[i-p0] = sci[b*3000 + i];
  __syncthreads();
  int co = t >> 3, kk = t & 7;
  const float* wrow = w + co*wstride + kk;
  float* Srow = S + (size_t)b*32*sstride + co*sstride + kk;
  for(int v=vs;v<ve;v++){
    int j = loff[v] - p0, je = loff[v+1] - p0;
    float a0=0.f,a1=0.f,a2=0.f,a3=0.f,a4=0.f,a5=0.f,a6=0.f,a7=0.f;
    for(; j+8 <= je; j += 8){
      a0 += wrow[lci[j]];
      a1 += wrow[lci[j+1]];
      a2 += wrow[lci[j+2]];
      a3 += wrow[lci[j+3]];
      a4 += wrow[lci[j+4]];
      a5 += wrow[lci[j+5]];
      a6 += wrow[lci[j+6]];
      a7 += wrow[lci[j+7]];
    }
    for(; j<je; j++) a0 += wrow[lci[j]];
    Srow[v*8] = ((a0+a1)+(a2+a3)) + ((a4+a5)+(a6+a7));
  }
}

__global__ __launch_bounds__(128) void k_y(const float* __restrict__ S1, const float* __restrict__ S2,
                                           const float* __restrict__ emb1, const float* __restrict__ emb2,
                                           const float* __restrict__ c1b, const float* __restrict__ c2b,
                                           float* __restrict__ ysum){
  __shared__ float em1[640];
  __shared__ float em2[8320];
  __shared__ float Sa[320];
  __shared__ float Sb[4160];
  int b = blockIdx.x, cg = blockIdx.y, t = threadIdx.x;
  for(int i=t;i<640;i+=128)  em1[i] = emb1[i];
  for(int i=t;i<8320;i+=128) em2[i] = emb2[i];
  for(int i=t;i<320;i+=128)  Sa[i] = S1[b*1280 + cg*320 + i];
  for(int i=t;i<4160;i+=128) Sb[i] = S2[(size_t)b*16640 + cg*4160 + i];
  __syncthreads();
  if(t >= 121) return;
  #pragma unroll
  for(int c8=0;c8<8;c8++){
    int co = cg*8 + c8;
    const float* sa = Sa + c8*40;
    float acc1 = c1b[co];
    #pragma unroll
    for(int v=0;v<5;v++)
      #pragma unroll
      for(int k=0;k<8;k++) acc1 = fmaf(sa[v*8+k], em1[v*128 + t + k], acc1);
    const float* sb = Sb + c8*520;
    float acc2 = c2b[co];
    for(int v=0;v<65;v++){
      #pragma unroll
      for(int k=0;k<8;k++) acc2 = fmaf(sb[v*8+k], em2[v*128 + t + k], acc2);
    }
    ysum[b*3872 + co*121 + t] = 0.5f*(acc1 + acc2);
  }
}

__global__ __launch_bounds__(256) void k_fcxr(const float* __restrict__ ysum, const float* __restrict__ fcw,
                                              const float* __restrict__ fcb, float* __restrict__ out){
  __shared__ float part[512];
  int bp = blockIdx.x, q = blockIdx.y, t = threadIdx.x;
  int b0 = bp*2;
  int ol = t >> 3;
  int o  = q*32 + ol;
  int slice = t & 7;
  const float4* ys0 = (const float4*)(ysum + b0*3872) + slice*121;
  const float4* ys1 = (const float4*)(ysum + (b0+1)*3872) + slice*121;
  const float4* wr  = (const float4*)(fcw + (size_t)o*3872) + slice*121;
  float acc0 = 0.f, acc1 = 0.f;
  for(int k=0;k<121;k++){
    float4 w4 = wr[k];
    float4 y0 = ys0[k], y1 = ys1[k];
    acc0 += y0.x*w4.x + y0.y*w4.y + y0.z*w4.z + y0.w*w4.w;
    acc1 += y1.x*w4.x + y1.y*w4.y + y1.z*w4.z + y1.w*w4.w;
  }
  part[t] = acc0;
  part[256+t] = acc1;
  __syncthreads();
  if(slice == 0){
    float s0 = fcb[o], s1 = fcb[o];
    #pragma unroll
    for(int i=0;i<8;i++){ s0 += part[ol*8 + i]; s1 += part[256 + ol*8 + i]; }
    out[b0*128 + o] = s0;
    out[(b0+1)*128 + o] = s1;
  }
}

extern "C" void kernel_launch(void* const* d_in, const int* in_sizes, int n_in,
                              void* d_out, int out_size, void* d_ws, size_t ws_size,
                              hipStream_t stream){
  const int*   g_rna = (const int*)  d_in[0];
  const int*   l_rna = (const int*)  d_in[1];
  const float* pro_x = (const float*)d_in[2];
  const int*   eidx  = (const int*)  d_in[3];
  const float* pro_w = (const float*)d_in[4];
  const int*   batch = (const int*)  d_in[5];
  const float* emb1  = (const float*)d_in[6];
  const float* emb2  = (const float*)d_in[7];
  const float* c1w   = (const float*)d_in[8];
  const float* c1b   = (const float*)d_in[9];
  const float* c2w   = (const float*)d_in[10];
  const float* c2b   = (const float*)d_in[11];
  const float* fcxw  = (const float*)d_in[12];
  const float* fcxb  = (const float*)d_in[13];
  const float* gcnw  = (const float*)d_in[14];
  const float* gcnb  = (const float*)d_in[15];
  const float* bnm   = (const float*)d_in[16];
  const float* bnv   = (const float*)d_in[17];
  const float* bnw   = (const float*)d_in[18];
  const float* bnb   = (const float*)d_in[19];
  const float* gwl   = (const float*)d_in[20];
  const float* gwr   = (const float*)d_in[21];
  const float* gatt  = (const float*)d_in[22];
  const float* gatb  = (const float*)d_in[23];
  const float* f1w   = (const float*)d_in[24];
  const float* f1b   = (const float*)d_in[25];
  const float* f2w   = (const float*)d_in[26];
  const float* f2b_  = (const float*)d_in[27];
  float* out = (float*)d_out;

  char* ws = (char*)d_ws;
  size_t off = 0;
  auto A = [&](size_t n)->char*{ char* p = ws + off; off = (off + n + 255) & ~(size_t)255; return p; };
  u64*   pk     = (u64*)  A((size_t)N_NODES*8);
  int*   fill   = (int*)  A((size_t)N_NODES*4);
  size_t zero_bytes = off;
  int*   rowptr = (int*)  A((size_t)(N_NODES+1)*4);
  int*   bsum   = (int*)  A(196*4);
  int*   bbase  = (int*)  A(196*4);
  uint2* s_srcw = (uint2*)A((size_t)N_EDGES*8);
  u32*   hb     = (u32*)  A((size_t)N_NODES*17*4);
  float* xp1    = (float*)A((size_t)N_NODES*36*4);
  u32*   xlb    = (u32*)  A((size_t)N_NODES*68*4);
  float* xr     = (float*)A((size_t)N_NODES*132*4);
  float* xp2    = (float*)A((size_t)N_NODES*132*4);
  int*   gstart = (int*)  A(64*4);
  int*   gend   = (int*)  A(64*4);
  float* pp     = (float*)A((size_t)64*16*132*4);
  float* h1T    = (float*)A(1024*64*4);
  float* S1     = (float*)A((size_t)64*1280*4);
  float* S2     = (float*)A((size_t)64*16640*4);
  float* ysum   = (float*)A((size_t)64*3872*4);
  int*   sci1   = (int*)  A((size_t)64*3000*4);
  int*   off1   = (int*)  A((size_t)64*8*4);
  int*   sci2   = (int*)  A((size_t)64*3000*4);
  int*   off2   = (int*)  A((size_t)64*66*4);
  (void)ws_size; (void)in_sizes; (void)n_in; (void)out_size;

  hipMemsetAsync(ws, 0, zero_bytes, stream);

  // protein GNN pipeline
  k_hist   <<<3125, 256, 0, stream>>>(eidx, pro_w, pk);
  k_scan1  <<<196, 256, 0, stream>>>(pk, rowptr, bsum);
  k_scan2  <<<1, 256, 0, stream>>>(bsum, bbase, rowptr, gstart, gend);
  k_scan3  <<<196, 256, 0, stream>>>(rowptr, bbase);
  k_scatter<<<3125, 256, 0, stream>>>(eidx, pro_w, rowptr, fill, pk, s_srcw);
  k_h      <<<196, 256, 0, stream>>>(pro_x, gcnw, hb);
  k_gcn    <<<12500, 256, 0, stream>>>(hb, rowptr, s_srcw, pk, gcnb, bnm, bnv, bnw, bnb, xp1);
  k_gatlin <<<782, 320, 0, stream>>>(xp1, gwl, gwr, xlb, xr);
  k_gat    <<<N_NODES, 128, 0, stream>>>(rowptr, (const u32*)s_srcw, xlb, xr, gatt, gatb, xp2);
  k_bounds <<<196, 256, 0, stream>>>(batch, gstart, gend);
  k_poolp  <<<dim3(64,16), 128, 0, stream>>>(xp2, gstart, gend, pp);
  k_pfc1   <<<64, 256, 0, stream>>>(pp, gstart, gend, f1w, f1b, h1T);
  k_fc2    <<<128, 256, 0, stream>>>(h1T, f2w, f2b_, out);

  // RNA branches
  k_bucket <<<64, 256, 0, stream>>>(g_rna, 3000, 5, sci1, off1);
  k_bucket <<<64, 256, 0, stream>>>(l_rna, 2998, 65, sci2, off2);
  k_sgather<<<dim3(64,5), 256, 0, stream>>>(sci1, off1, c1w, 5, 24000, 40, S1);
  k_sgather<<<dim3(64,32), 256, 0, stream>>>(sci2, off2, c2w, 65, 23984, 520, S2);
  k_y      <<<dim3(64,4), 128, 0, stream>>>(S1, S2, emb1, emb2, c1b, c2b, ysum);
  k_fcxr   <<<dim3(32,4), 256, 0, stream>>>(ysum, fcxw, fcxb, out);
}